// Round 1
// baseline (1996.267 us; speedup 1.0000x reference)
//
#include <hip/hip_runtime.h>
#include <math.h>

// ============================================================================
// ConflictNet: 30-step graph-PDE scan, B=2, N=8000, DY=12.
// Strategy: one kernel per scan step (kernel boundary = global barrier for the
// scatter), scatter converted to gather via precomputed reverse adjacency.
// Wave-per-node; MLP activations broadcast with __shfl (readlane).
// ============================================================================

namespace {
constexpr int NB = 2;
constexpr int NN = 8000;
constexpr int BN = NB * NN;   // 16000
constexpr int TS = 30;
constexpr int CAP = 96;       // reverse-adjacency capacity (Poisson(25) max ~55)

// workspace float offsets
constexpr int O_COEFF = 0;              // 12x12 coeffM
constexpr int O_DIJ   = 144;            // 12
constexpr int O_MUIJ  = 156;            // 12
constexpr int O_MC    = 168;            // 12  (MUij @ coeffM)
constexpr int O_GPX   = 256;            // BN
constexpr int O_GPY   = O_GPX + BN;
constexpr int O_H1T   = O_GPY + BN;     // BN*64  trans layer-0 static (incl bias)
constexpr int O_H1Q   = O_H1T + BN*64;  // BN*64  q layer-0 static
constexpr int O_H1D   = O_H1Q + BN*64;  // BN*32  dec layer-0 static
constexpr int O_FEATA = O_H1D + BN*32;  // BN*12
constexpr int O_FEATB = O_FEATA + BN*12;
constexpr int O_AXYA  = O_FEATB + BN*12; // BN*24 (ax[12], ay[12])
constexpr int O_AXYB  = O_AXYA + BN*24;
constexpr int O_FLTEND= O_AXYB + BN*24;
// int region (after float region): rev counts [BN], rev entries [BN*CAP]

// output flat offsets
constexpr int OUS  = 0;                 // us   (B,N,1,T)
constexpr int OMIX = BN*TS;             // mix  (B,N,1,T)
constexpr int OQ0  = 2*BN*TS;           // q0_m (B,N,12,1,T)
constexpr int OFD  = OQ0 + BN*12*TS;    // fd   (B,N,1,T,12)
}

__device__ __forceinline__ float group5_sum(float v, int lane) {
  // lanes are (g, c) = (lane/12, lane%12), g<5 active; sum across the 5 groups.
  int g = lane / 12, c = lane % 12;
  float s1 = __shfl(v, c + 12*((g+1)%5));
  float s2 = __shfl(v, c + 12*((g+2)%5));
  float s3 = __shfl(v, c + 12*((g+3)%5));
  float s4 = __shfl(v, c + 12*((g+4)%5));
  return v + s1 + s2 + s3 + s4;
}

// ---------------------------------------------------------------------------
// S1: coeffM (12x12), Dij, MUij, MC = MUij @ coeffM
// ---------------------------------------------------------------------------
__global__ void k_setup_small(const float* __restrict__ D, const float* __restrict__ mu,
                              const float* __restrict__ cv, float* ws) {
  int t = threadIdx.x;
  for (int e = t; e < 144; e += 256) {
    int r = e / 12, q = e % 12;
    int rb = r >> 2, cb = q >> 2, ri = r & 3, qi = q & 3;
    float val = 0.f;
    if (rb == cb) {
      int f = ri*4 + qi;      // index into flattened [1,a..,1,a..,1,a..,1]
      if (f % 5 == 0) val = 1.f;
      else val = cv[64 + rb*12 + (f/5)*4 + (f%5) - 1];
    } else if (rb == 0 && cb == 2) val = cv[     ri*4 + qi];
    else if   (rb == 1 && cb == 2) val = cv[16 + ri*4 + qi];
    else if   (rb == 2 && cb == 0) val = cv[32 + ri*4 + qi];
    else if   (rb == 2 && cb == 1) val = cv[48 + ri*4 + qi];
    ws[O_COEFF + e] = fmaxf(val, 0.f);
  }
  if (t < 12) {
    ws[O_DIJ + t]  = (t < 4) ? 0.f : fmaxf(D[t-4], 0.f);
    ws[O_MUIJ + t] = (t < 4) ? fmaxf(mu[t], 0.f) : ((t < 8) ? 0.f : fmaxf(mu[t-4], 0.f));
  }
  __syncthreads();
  if (t < 12) {
    float acc = 0.f;
    for (int c = 0; c < 12; c++) acc += ws[O_MUIJ + c] * ws[O_COEFF + c*12 + t];
    ws[O_MC + t] = acc;
  }
}

// ---------------------------------------------------------------------------
// S2: per-node invariants: gpx/gpy, layer-0 static h1 biases, feat copy,
//     initial ax/ay, zero rev counts.  Wave per node.
// ---------------------------------------------------------------------------
__global__ __launch_bounds__(256) void k_setup_node(
    const float* __restrict__ phi, const float* __restrict__ feat_dy,
    const float* __restrict__ feat_st,
    const int* __restrict__ adj4, const int* __restrict__ adj25,
    const float* __restrict__ Wt0, const float* __restrict__ bt0,
    const float* __restrict__ Wq0, const float* __restrict__ bq0,
    const float* __restrict__ Wd0, const float* __restrict__ bd0,
    float* ws, int* wsi) {
  const int wid  = (blockIdx.x * blockDim.x + threadIdx.x) >> 6;
  const int lane = threadIdx.x & 63;
  if (wid >= BN) return;
  const int b = wid / NN, n = wid % NN;

  const int* a4 = adj4 + n*4;                       // batch-0 adjacency (ref uses adj4[0])
  const float gpx = phi[b*NN + a4[1]] - phi[b*NN + a4[0]];  // /(2*DX)=1
  const float gpy = phi[b*NN + a4[3]] - phi[b*NN + a4[2]];
  if (lane == 0) { ws[O_GPX + wid] = gpx; ws[O_GPY + wid] = gpy; wsi[wid] = 0; }

  int idx = 0; float w = 0.f;
  if (lane < 25) { idx = adj25[n*25 + lane]; w = (lane == 0) ? 1.f : 0.01f; }  // adj25[0]
  float phiw = (lane < 25) ? w * phi[b*NN + idx] : 0.f;
  #pragma unroll
  for (int s = 32; s > 0; s >>= 1) phiw += __shfl_xor(phiw, s);

  float stv[6], stw[6];
  #pragma unroll
  for (int j = 0; j < 6; j++) {
    float x = (lane < 25) ? w * feat_st[(b*NN + idx)*6 + j] : 0.f;
    #pragma unroll
    for (int s = 32; s > 0; s >>= 1) x += __shfl_xor(x, s);
    stw[j] = x;
    stv[j] = feat_st[(b*NN + n)*6 + j];
  }
  const float phiv = phi[b*NN + n];

  // feat_tr rows: 0-23 ag | 24-25 phi_ag | 26-37 D | 38-49 MU | 50-61 st_ag
  float hT = bt0[lane] + phiv*Wt0[24*64 + lane] + phiw*Wt0[25*64 + lane];
  // feat_q rows: 0-23 ag | 24-25 phi_ag | 26-37 st_ag
  float hQ = bq0[lane] + phiv*Wq0[24*64 + lane] + phiw*Wq0[25*64 + lane];
  #pragma unroll
  for (int i = 0; i < 12; i++) {
    hT = fmaf(ws[O_DIJ  + i], Wt0[(26+i)*64 + lane], hT);
    hT = fmaf(ws[O_MUIJ + i], Wt0[(38+i)*64 + lane], hT);
  }
  #pragma unroll
  for (int j = 0; j < 6; j++) {
    hT = fmaf(stv[j], Wt0[(50+j)*64 + lane], hT);
    hT = fmaf(stw[j], Wt0[(56+j)*64 + lane], hT);
    hQ = fmaf(stv[j], Wq0[(26+j)*64 + lane], hQ);
    hQ = fmaf(stw[j], Wq0[(32+j)*64 + lane], hQ);
  }
  ws[O_H1T + wid*64 + lane] = hT;
  ws[O_H1Q + wid*64 + lane] = hQ;
  if (lane < 32) {
    float hD = bd0[lane];                            // dec rows 12-17: feat_st (own)
    #pragma unroll
    for (int j = 0; j < 6; j++) hD = fmaf(stv[j], Wd0[(12+j)*32 + lane], hD);
    ws[O_H1D + wid*32 + lane] = hD;
  }
  if (lane < 12) {
    float f = feat_dy[wid*12 + lane];
    ws[O_FEATA + wid*12 + lane] = f;
    float mass = (f == 0.f) ? 1.f : f;
    float mc = ws[O_MC + lane];
    ws[O_AXYA + wid*24 + lane]      = fminf(fmaxf(gpx*mc/mass, -2.f), 2.f);
    ws[O_AXYA + wid*24 + 12 + lane] = fminf(fmaxf(gpy*mc/mass, -2.f), 2.f);
  }
}

// ---------------------------------------------------------------------------
// S3: build reverse adjacency for the scatter (per batch).
// ---------------------------------------------------------------------------
__global__ void k_build_rev(const int* __restrict__ adj25, int* wsi) {
  int i = blockIdx.x * blockDim.x + threadIdx.x;
  if (i >= BN * 25) return;
  int b = i / (NN * 25);
  int rem = i % (NN * 25);
  int m = rem / 25, k = rem % 25;
  int tgt = adj25[i];
  int slot = atomicAdd(&wsi[b*NN + tgt], 1);
  if (slot < CAP) wsi[BN + (b*NN + tgt)*CAP + slot] = (m << 5) | k;
}

// ---------------------------------------------------------------------------
// Step kernel: one scan iteration.  Wave per node.
// ---------------------------------------------------------------------------
__global__ __launch_bounds__(256) void k_step(
    const float* ws, const int* rcnt, const int* rent, int t,
    const float* fsrc, const float* axsrc, float* fdst, float* axdst,
    const int* __restrict__ adj4, const int* __restrict__ adj25,
    const float* __restrict__ Wt0, const float* __restrict__ Wq0,
    const float* __restrict__ Wt1, const float* __restrict__ bt1,
    const float* __restrict__ Wq1, const float* __restrict__ bq1,
    const float* __restrict__ Wt2, const float* __restrict__ bt2,
    const float* __restrict__ Wq2, const float* __restrict__ bq2,
    const float* __restrict__ Wd0, const float* __restrict__ Wd1,
    const float* __restrict__ bd1, const float* __restrict__ Wd2,
    const float* __restrict__ bd2, const float* __restrict__ Wd3,
    const float* __restrict__ bd3, float* __restrict__ out) {
  const int wid  = (blockIdx.x * blockDim.x + threadIdx.x) >> 6;
  const int lane = threadIdx.x & 63;
  if (wid >= BN) return;
  const int b = wid / NN, n = wid % NN;
  const int c12 = lane % 12;
  const int g   = lane / 12;

  const float f_c = fsrc[wid*12 + c12];   // every lane holds feat[lane%12]

  // ---- 25-neighbor weighted aggregate of feat (batch-0 adjacency) ----
  float agw = 0.f;
  {
    const int* a0 = adj25 + n*25;
    if (g < 5) {
      #pragma unroll
      for (int kk = 0; kk < 5; kk++) {
        int k = g + 5*kk;
        int idx = a0[k];
        float wgt = (k == 0) ? 1.f : 0.01f;
        agw = fmaf(wgt, fsrc[(b*NN + idx)*12 + c12], agw);
      }
    }
    agw = group5_sum(agw, lane);
  }
  const float AG = (lane < 12) ? f_c : agw;   // lanes 0-11: feat, 12-23: wsum

  // ---- J, Fdiv, u_diff ----
  const int* a4 = adj4 + n*4;
  const int n0 = a4[0], n1 = a4[1], n2 = a4[2], n3 = a4[3];
  const float f0 = fsrc[(b*NN+n0)*12 + c12];
  const float f1 = fsrc[(b*NN+n1)*12 + c12];
  const float f2 = fsrc[(b*NN+n2)*12 + c12];
  const float f3 = fsrc[(b*NN+n3)*12 + c12];
  const float J = 4.f * ((f0+f1+f2+f3) - 4.f*f_c);   // /DX^2 + /DYG^2, DX=DYG=0.5
  const float gx0 = ws[O_GPX + b*NN + n0], gx1 = ws[O_GPX + b*NN + n1];
  const float gy2 = ws[O_GPY + b*NN + n2], gy3 = ws[O_GPY + b*NN + n3];
  const float Fdiv = gx1*f1 - gx0*f0 + gy3*f3 - gy2*f2;   // /(2DX)=/(2DYG)=1
  const float v = ws[O_DIJ + c12]*J - ws[O_MUIJ + c12]*Fdiv;
  float udiff = 0.f;
  #pragma unroll
  for (int cc = 0; cc < 12; cc++) {
    float s = __shfl(v, cc);
    udiff = fmaf(s, ws[O_COEFF + cc*12 + c12], udiff);
  }

  // ---- u_rig via reverse-adjacency gather (replaces scatter-add) ----
  float usc = 0.f;
  {
    int cnt = rcnt[wid]; if (cnt > CAP) cnt = CAP;
    const int* re = rent + wid*CAP;
    if (g < 5) {
      for (int e = g; e < cnt; e += 5) {
        int pk = re[e];
        int m = pk >> 5, k = pk & 31;
        float kx = (float)(k - (k/5)*5);
        float ky = (float)(k/5);
        int base = b*NN + m;
        float fm = fsrc[base*12 + c12];
        float ax = axsrc[base*24 + c12];
        float ay = axsrc[base*24 + 12 + c12];
        float px = fmaxf(1.f - fabsf(ax - kx), 0.f);
        float py = fmaxf(1.f - fabsf(ay - ky), 0.f);
        usc = fmaf(px*py, fm, usc);
      }
    }
    usc = group5_sum(usc, lane);
  }
  const float urig = usc - f_c;

  // ---- trans & q hidden-1 (64 wide, dynamic part: 24 ag rows) ----
  float h1t = ws[O_H1T + wid*64 + lane];
  float h1q = ws[O_H1Q + wid*64 + lane];
  #pragma unroll
  for (int i = 0; i < 24; i++) {
    float a = __shfl(AG, i);
    h1t = fmaf(a, Wt0[i*64 + lane], h1t);
    h1q = fmaf(a, Wq0[i*64 + lane], h1q);
  }
  h1t = fmaxf(h1t, 0.f);
  h1q = fmaxf(h1q, 0.f);

  // ---- hidden-2: lanes 0-31 trans, lanes 32-63 q ----
  const int l32 = lane & 31;
  const bool isQ = lane >= 32;
  const float* W1p = isQ ? (Wq1 + l32) : (Wt1 + l32);
  float h2 = isQ ? bq1[l32] : bt1[l32];
  #pragma unroll
  for (int i = 0; i < 64; i++) {
    float st = __shfl(h1t, i);
    float sq = __shfl(h1q, i);
    h2 = fmaf(isQ ? sq : st, W1p[i*32], h2);
  }
  h2 = fmaxf(h2, 0.f);

  // ---- mix logit (only col 25 of Wt2) + q0 (12 outputs on lanes 0-11) ----
  float mixz = bt2[25];
  const float* Wq2p = Wq2 + ((lane < 12) ? lane : 11);
  float q0 = bq2[(lane < 12) ? lane : 11];
  #pragma unroll
  for (int i = 0; i < 32; i++) {
    float st = __shfl(h2, i);        // h2t[i]
    float sq = __shfl(h2, 32 + i);   // h2q[i]
    mixz = fmaf(st, Wt2[i*26 + 25], mixz);
    q0   = fmaf(sq, Wq2p[i*12], q0);
  }
  const float mix = 1.f / (1.f + expf(-mixz));

  // ---- update + per-channel outputs + next-step ax/ay ----
  const float newv = f_c + mix*udiff + (1.f - mix)*urig + q0;   // lanes 0-11 valid
  if (lane < 12) {
    out[OQ0 + (wid*12 + lane)*TS + t] = q0;
    out[OFD + (wid*TS + t)*12 + lane] = newv;
    fdst[wid*12 + lane] = newv;
    float mass = (newv == 0.f) ? 1.f : newv;
    float mc = ws[O_MC + lane];
    float gpxn = ws[O_GPX + wid], gpyn = ws[O_GPY + wid];
    axdst[wid*24 + lane]      = fminf(fmaxf(gpxn*mc/mass, -2.f), 2.f);
    axdst[wid*24 + 12 + lane] = fminf(fmaxf(gpyn*mc/mass, -2.f), 2.f);
  }
  if (lane == 0) out[OMIX + wid*TS + t] = mix;

  // ---- dec MLP: 12(+static feat_st) -> 32 -> 32 -> 64 -> 1 ----
  float d1 = ws[O_H1D + wid*32 + l32];
  #pragma unroll
  for (int i = 0; i < 12; i++) {
    float s = __shfl(newv, i);
    d1 = fmaf(s, Wd0[i*32 + l32], d1);
  }
  d1 = fmaxf(d1, 0.f);
  float d2 = bd1[l32];
  #pragma unroll
  for (int i = 0; i < 32; i++) {
    float s = __shfl(d1, i);
    d2 = fmaf(s, Wd1[i*32 + l32], d2);
  }
  d2 = fmaxf(d2, 0.f);
  float d3 = bd2[lane];
  #pragma unroll
  for (int i = 0; i < 32; i++) {
    float s = __shfl(d2, i);
    d3 = fmaf(s, Wd2[i*64 + lane], d3);
  }
  d3 = fmaxf(d3, 0.f);
  float usp = d3 * Wd3[lane];
  #pragma unroll
  for (int s2 = 32; s2 > 0; s2 >>= 1) usp += __shfl_xor(usp, s2);
  if (lane == 0) out[OUS + wid*TS + t] = usp + bd3[0];
}

// ---------------------------------------------------------------------------
extern "C" void kernel_launch(void* const* d_in, const int* in_sizes, int n_in,
                              void* d_out, int out_size, void* d_ws, size_t ws_size,
                              hipStream_t stream) {
  const float* phi     = (const float*)d_in[0];
  const float* feat_dy = (const float*)d_in[1];
  const float* feat_st = (const float*)d_in[2];
  const float* Dv      = (const float*)d_in[3];
  const float* muv     = (const float*)d_in[4];
  const float* cv      = (const float*)d_in[5];
  const int*   adj4    = (const int*)d_in[6];
  const int*   adj25   = (const int*)d_in[7];
  const float* Wt0 = (const float*)d_in[8];
  const float* bt0 = (const float*)d_in[9];
  const float* Wt1 = (const float*)d_in[10];
  const float* bt1 = (const float*)d_in[11];
  const float* Wt2 = (const float*)d_in[12];
  const float* bt2 = (const float*)d_in[13];
  const float* Wq0 = (const float*)d_in[14];
  const float* bq0 = (const float*)d_in[15];
  const float* Wq1 = (const float*)d_in[16];
  const float* bq1 = (const float*)d_in[17];
  const float* Wq2 = (const float*)d_in[18];
  const float* bq2 = (const float*)d_in[19];
  const float* Wd0 = (const float*)d_in[20];
  const float* bd0 = (const float*)d_in[21];
  const float* Wd1 = (const float*)d_in[22];
  const float* bd1 = (const float*)d_in[23];
  const float* Wd2 = (const float*)d_in[24];
  const float* bd2 = (const float*)d_in[25];
  const float* Wd3 = (const float*)d_in[26];
  const float* bd3 = (const float*)d_in[27];

  float* ws  = (float*)d_ws;
  int*   wsi = (int*)(ws + O_FLTEND);
  float* out = (float*)d_out;

  k_setup_small<<<1, 256, 0, stream>>>(Dv, muv, cv, ws);
  k_setup_node<<<BN/4, 256, 0, stream>>>(phi, feat_dy, feat_st, adj4, adj25,
                                         Wt0, bt0, Wq0, bq0, Wd0, bd0, ws, wsi);
  k_build_rev<<<(BN*25 + 255)/256, 256, 0, stream>>>(adj25, wsi);

  float* fa = ws + O_FEATA; float* fb = ws + O_FEATB;
  float* aa = ws + O_AXYA;  float* ab = ws + O_AXYB;
  for (int t = 0; t < TS; t++) {
    k_step<<<BN/4, 256, 0, stream>>>(ws, wsi, wsi + BN, t, fa, aa, fb, ab,
                                     adj4, adj25,
                                     Wt0, Wq0, Wt1, bt1, Wq1, bq1,
                                     Wt2, bt2, Wq2, bq2,
                                     Wd0, Wd1, bd1, Wd2, bd2, Wd3, bd3, out);
    float* tf = fa; fa = fb; fb = tf;
    float* ta = aa; aa = ab; ab = ta;
  }
}